// Round 2
// baseline (382.005 us; speedup 1.0000x reference)
//
#include <hip/hip_runtime.h>
#include <hip/hip_bf16.h>

#define BATCH 4
#define NQ 4096
#define NK 4096
#define DIM 64

typedef __attribute__((ext_vector_type(8))) short bf16x8;
typedef __attribute__((ext_vector_type(4))) float f32x4;

// round-to-nearest-even f32 -> bf16
__device__ __forceinline__ unsigned short f2bf(float f) {
  union { float f; unsigned u; } v; v.f = f;
  return (unsigned short)((v.u + 0x7FFF + ((v.u >> 16) & 1)) >> 16);
}

// Stage a ROWS x 64 f32 row-major tile (contiguous) into LDS as bf16 with
// 16B-slot XOR swizzle (slot ^= row&7, row stride 128B), and compute per-row
// sum of squares in f32 from the original global data.
template<int ROWS>
__device__ __forceinline__ void stage_tile(const float* __restrict__ g, char* lds,
                                           float* sq, int tid) {
  constexpr int NV = ROWS * 16;  // number of float4 chunks
  #pragma unroll
  for (int i = 0; i < NV / 256; ++i) {
    const int idx = i * 256 + tid;
    const float4 v = reinterpret_cast<const float4*>(g)[idx];
    const int f = idx * 4;
    const int row = f >> 6, col = f & 63;
    uint2 pk;
    pk.x = (unsigned)f2bf(v.x) | ((unsigned)f2bf(v.y) << 16);
    pk.y = (unsigned)f2bf(v.z) | ((unsigned)f2bf(v.w) << 16);
    const int byte = row * 128 + ((((col >> 3) ^ (row & 7)) << 4)) + ((col >> 2) & 1) * 8;
    *reinterpret_cast<uint2*>(lds + byte) = pk;
  }
  if (tid < ROWS) {
    const float4* rp = reinterpret_cast<const float4*>(g + tid * DIM);
    float s = 0.f;
    #pragma unroll
    for (int j = 0; j < 16; ++j) {
      const float4 v = rp[j];
      s += v.x * v.x + v.y * v.y + v.z * v.z + v.w * v.w;
    }
    sq[tid] = s;
  }
}

// Load one 16x32 MFMA operand fragment (8 bf16 per lane) from swizzled LDS.
// lane l holds row (base row given), k = ks*32 + (l>>4)*8 + j  (j=0..7)
__device__ __forceinline__ bf16x8 frag_load(const char* lds, int row, int ks, int lane) {
  return *reinterpret_cast<const bf16x8*>(
      lds + row * 128 + (((ks * 4 + (lane >> 4)) ^ (row & 7)) << 4));
}

// Kernel 1: partial row sums of exp(-sqrt(max(q2+k2-2qk,0))/8).
// grid (4 colsplit, NQ/64, BATCH), block 256. No max-subtraction needed: s<=0 always.
__global__ __launch_bounds__(256) void k_rowsum(
    const float* __restrict__ Qg, const float* __restrict__ Kg,
    float* __restrict__ partials) {
  __shared__ char Qlds[64 * 128];
  __shared__ char Klds[256 * 128];
  __shared__ float q2[64];
  __shared__ float k2[256];
  const int tid = threadIdx.x;
  const int cs = blockIdx.x;
  const int brow = blockIdx.y * 64;
  const int b = blockIdx.z;
  const float* Qb = Qg + ((size_t)b * NQ + brow) * DIM;
  const float* Kb = Kg + (size_t)b * NK * DIM;

  stage_tile<64>(Qb, Qlds, q2, tid);
  __syncthreads();

  const int lane = tid & 63, w = tid >> 6;
  const int arow = w * 16 + (lane & 15);
  const bf16x8 af0 = frag_load(Qlds, arow, 0, lane);
  const bf16x8 af1 = frag_load(Qlds, arow, 1, lane);
  float q2r[4];
  #pragma unroll
  for (int i = 0; i < 4; ++i) q2r[i] = q2[w * 16 + (lane >> 4) * 4 + i];

  float sums[4] = {0.f, 0.f, 0.f, 0.f};
  for (int t = 0; t < 4; ++t) {
    __syncthreads();  // previous tile's reads complete before overwrite
    stage_tile<256>(Kb + ((size_t)(cs * 4 + t)) * 256 * DIM, Klds, k2, tid);
    __syncthreads();
    #pragma unroll
    for (int c = 0; c < 16; ++c) {
      const int krow = c * 16 + (lane & 15);
      const bf16x8 bf0 = frag_load(Klds, krow, 0, lane);
      const bf16x8 bf1 = frag_load(Klds, krow, 1, lane);
      f32x4 acc = {0.f, 0.f, 0.f, 0.f};
      acc = __builtin_amdgcn_mfma_f32_16x16x32_bf16(af0, bf0, acc, 0, 0, 0);
      acc = __builtin_amdgcn_mfma_f32_16x16x32_bf16(af1, bf1, acc, 0, 0, 0);
      const float k2c = k2[krow];
      #pragma unroll
      for (int i = 0; i < 4; ++i) {
        const float d2 = fmaxf(q2r[i] + k2c - 2.f * acc[i], 0.f);
        sums[i] += __expf(-sqrtf(d2) * 0.125f);
      }
    }
  }
  // reduce across the 16 lanes sharing the same output rows (lane&15 varies)
  #pragma unroll
  for (int m = 1; m < 16; m <<= 1) {
    #pragma unroll
    for (int i = 0; i < 4; ++i) sums[i] += __shfl_xor(sums[i], m, 64);
  }
  if ((lane & 15) == 0) {
    const int r = brow + w * 16 + (lane >> 4) * 4;
    #pragma unroll
    for (int i = 0; i < 4; ++i)
      partials[((size_t)cs * BATCH + b) * NQ + r + i] = sums[i];
  }
}

// Kernel 2: recompute scores, write exp(s) * inv_rowsum.
// grid (NK/256, NQ/64, BATCH), block 256.
__global__ __launch_bounds__(256) void k_softmax(
    const float* __restrict__ Qg, const float* __restrict__ Kg,
    const float* __restrict__ partials, float* __restrict__ out) {
  __shared__ char Qlds[64 * 128];
  __shared__ char Klds[256 * 128];
  __shared__ float q2[64];
  __shared__ float k2[256];
  const int tid = threadIdx.x;
  const int bcol = blockIdx.x * 256;
  const int brow = blockIdx.y * 64;
  const int b = blockIdx.z;
  const float* Qb = Qg + ((size_t)b * NQ + brow) * DIM;
  const float* Kb = Kg + ((size_t)b * NK + bcol) * DIM;

  stage_tile<64>(Qb, Qlds, q2, tid);
  stage_tile<256>(Kb, Klds, k2, tid);
  __syncthreads();

  const int lane = tid & 63, w = tid >> 6;
  const int arow = w * 16 + (lane & 15);
  const bf16x8 af0 = frag_load(Qlds, arow, 0, lane);
  const bf16x8 af1 = frag_load(Qlds, arow, 1, lane);

  float q2r[4], inv[4];
  size_t rowbase[4];
  #pragma unroll
  for (int i = 0; i < 4; ++i) {
    const int r = w * 16 + (lane >> 4) * 4 + i;
    q2r[i] = q2[r];
    const int gr = brow + r;
    float s = 0.f;
    #pragma unroll
    for (int cs = 0; cs < 4; ++cs) s += partials[((size_t)cs * BATCH + b) * NQ + gr];
    inv[i] = 1.0f / s;
    rowbase[i] = ((size_t)b * NQ + gr) * NK + bcol;
  }

  #pragma unroll
  for (int c = 0; c < 16; ++c) {
    const int krow = c * 16 + (lane & 15);
    const bf16x8 bf0 = frag_load(Klds, krow, 0, lane);
    const bf16x8 bf1 = frag_load(Klds, krow, 1, lane);
    f32x4 acc = {0.f, 0.f, 0.f, 0.f};
    acc = __builtin_amdgcn_mfma_f32_16x16x32_bf16(af0, bf0, acc, 0, 0, 0);
    acc = __builtin_amdgcn_mfma_f32_16x16x32_bf16(af1, bf1, acc, 0, 0, 0);
    const float k2c = k2[krow];
    const int col = c * 16 + (lane & 15);
    #pragma unroll
    for (int i = 0; i < 4; ++i) {
      const float d2 = fmaxf(q2r[i] + k2c - 2.f * acc[i], 0.f);
      out[rowbase[i] + col] = __expf(-sqrtf(d2) * 0.125f) * inv[i];
    }
  }
}

extern "C" void kernel_launch(void* const* d_in, const int* in_sizes, int n_in,
                              void* d_out, int out_size, void* d_ws, size_t ws_size,
                              hipStream_t stream) {
  const float* Q = (const float*)d_in[0];
  const float* K = (const float*)d_in[1];
  float* out = (float*)d_out;
  float* partials = (float*)d_ws;  // 4 colsplits * 4 batches * 4096 rows * 4B = 256 KB

  k_rowsum<<<dim3(4, NQ / 64, BATCH), dim3(256), 0, stream>>>(Q, K, partials);
  k_softmax<<<dim3(NK / 256, NQ / 64, BATCH), dim3(256), 0, stream>>>(Q, K, partials, out);
}